// Round 3
// baseline (2121.896 us; speedup 1.0000x reference)
//
#include <hip/hip_runtime.h>
#include <math.h>

#define B_ 16
#define T_ 4096
#define D_ 1024
#define HID_ 1365
#define NPAD 1408            // 88*16
#define NGRP 88              // NPAD/16
#define N_TOK (B_*T_)
#define RHO_ 0.2f
#define LN_EPS_ 1e-5f
#define SC 1024.0f
#define INV_SC2 (1.0f/(1024.0f*1024.0f))

#define NHT 11               // h-tiles of 128
#define WCHUNKS (NGRP*32*4*16)       // 180224 f16x8 chunks
#define NG16 4096            // 16-token groups
#define ACHUNKS ((size_t)NG16*32*64) // 8388608 f16x8 chunks per buffer

// fallback (round-2) tiling
#define MT 128
#define HT 128
#define KSTEPS 32
#define LDA 40

typedef _Float16 f16x8 __attribute__((ext_vector_type(8)));
typedef _Float16 f16x4 __attribute__((ext_vector_type(4)));
typedef float f32x4 __attribute__((ext_vector_type(4)));

// ---------------- Kernel 1: LayerNorm statistics (one wave per token) ----------------
__global__ __launch_bounds__(256) void ln_stats_kernel(
    const float* __restrict__ emb, const float* __restrict__ attn,
    float* __restrict__ mu, float* __restrict__ rstd)
{
  int tid = threadIdx.x;
  int wave = tid >> 6, lane = tid & 63;
  int token = blockIdx.x * 4 + wave;
  const float* p = emb + (size_t)token * D_;
  float a = attn[token];
  float s = 0.f, sq = 0.f;
#pragma unroll
  for (int q = 0; q < 4; ++q) {
    float4 v = *reinterpret_cast<const float4*>(p + lane * 4 + q * 256);
    v.x *= a; v.y *= a; v.z *= a; v.w *= a;
    s  += v.x + v.y + v.z + v.w;
    sq += v.x * v.x + v.y * v.y + v.z * v.z + v.w * v.w;
  }
#pragma unroll
  for (int off = 32; off > 0; off >>= 1) {
    s  += __shfl_down(s, off, 64);
    sq += __shfl_down(sq, off, 64);
  }
  if (lane == 0) {
    float m = s * (1.f / D_);
    float var = sq * (1.f / D_) - m * m;
    if (var < 0.f) var = 0.f;
    mu[token] = m;
    rstd[token] = 1.f / sqrtf(var + LN_EPS_);
  }
}

// ---------------- Kernel 1b: split fc1_w (x1024) into hi/lo f16 in MFMA-frag order ---
// c -> ln=c&15, q=(c>>4)&3, ks=(c>>6)&31, g=c>>11 ; n=g*16+ln, k=ks*32+q*8
__global__ __launch_bounds__(256) void wsplit_kernel(
    const float* __restrict__ fc1w, f16x8* __restrict__ whi, f16x8* __restrict__ wlo)
{
  int c = blockIdx.x * 256 + threadIdx.x;
  if (c >= WCHUNKS) return;
  int ln = c & 15, q = (c >> 4) & 3, ks = (c >> 6) & 31, g = c >> 11;
  int n = g * 16 + ln;
  int k = ks * 32 + q * 8;
  f16x8 hi, lo;
#pragma unroll
  for (int j = 0; j < 8; ++j) {
    float v = (n < HID_) ? fc1w[(size_t)n * D_ + k + j] * SC : 0.f;
    _Float16 h = (_Float16)v;
    hi[j] = h;
    lo[j] = (_Float16)(v - (float)h);
  }
  whi[c] = hi;
  wlo[c] = lo;
}

// ---------------- Kernel 1c: LN-apply + split A into hi/lo f16, MFMA-frag order ------
// block = one 16-token group x 512-k half; LDS transpose for coalescing both sides
#define ASTRIDE 516
__global__ __launch_bounds__(256) void asplit_kernel(
    const float* __restrict__ emb, const float* __restrict__ attn,
    const float* __restrict__ mu, const float* __restrict__ rstd,
    const float* __restrict__ lnw, const float* __restrict__ lnb,
    f16x8* __restrict__ ahi, f16x8* __restrict__ alo)
{
  __shared__ float tile[16 * ASTRIDE];
  int tid = threadIdx.x;
  int g = blockIdx.x >> 1, kh = blockIdx.x & 1;
  int kbase = kh * 512;
  // stage in: 16 tokens x 512 k, coalesced
#pragma unroll
  for (int it = 0; it < 8; ++it) {
    int idx = tid + it * 256;          // 0..2047 float4-slots
    int row = idx >> 7, c4 = idx & 127;
    float4 v = *reinterpret_cast<const float4*>(
        emb + (size_t)(g * 16 + row) * D_ + kbase + c4 * 4);
    *reinterpret_cast<float4*>(&tile[row * ASTRIDE + c4 * 4]) = v;
  }
  __syncthreads();
  // stage out: frag-order chunks, fully coalesced 16B/lane writes
#pragma unroll
  for (int it = 0; it < 4; ++it) {
    int idx = tid + it * 256;          // 0..1023
    int ksl = idx >> 6, l = idx & 63;
    int ln = l & 15, q = l >> 4;
    int token = g * 16 + ln;
    float a = attn[token], rs = rstd[token];
    float alpha = a * rs;
    float nmr = -mu[token] * rs;
    int colbase = ksl * 32 + q * 8;
    float4 e0 = *reinterpret_cast<const float4*>(&tile[ln * ASTRIDE + colbase]);
    float4 e1 = *reinterpret_cast<const float4*>(&tile[ln * ASTRIDE + colbase + 4]);
    float ev[8] = {e0.x, e0.y, e0.z, e0.w, e1.x, e1.y, e1.z, e1.w};
    f16x8 hi, lo;
#pragma unroll
    for (int j = 0; j < 8; ++j) {
      int kg = kbase + colbase + j;
      float wv = lnw[kg], bv = lnb[kg];
      float y = fmaf(ev[j] * alpha, wv, fmaf(nmr, wv, bv)) * SC;
      _Float16 h = (_Float16)y;
      hi[j] = h;
      lo[j] = (_Float16)(y - (float)h);
    }
    size_t c = (size_t)(g * 32 + kh * 16 + ksl) * 64 + l;
    ahi[c] = hi;
    alo[c] = lo;
  }
}

// ---------------- Kernel 2 (v3): barrier-free frag-streaming MFMA GEMM --------------
// grid (NHT, 256 token-tiles); 256 thr = 4 waves 2x2; wave tile 128 tokens x 64 h
__global__ __launch_bounds__(256) void mfma_score_v3(
    const f16x8* __restrict__ ahi, const f16x8* __restrict__ alo,
    const f16x8* __restrict__ whi, const f16x8* __restrict__ wlo,
    const float* __restrict__ fc1b, const float* __restrict__ fc2w,
    float* __restrict__ partial)
{
  __shared__ float red[2][256];
  int tid = threadIdx.x, lane = tid & 63;
  int w = tid >> 6, wrow = w & 1, wcol = w >> 1;
  int ht = blockIdx.x;
  int tb = blockIdx.y;
  int g0 = tb * 16 + wrow * 8;       // 8 token-groups of 16 per wave
  int gb0 = ht * 8 + wcol * 4;       // 4 h-groups of 16 per wave
  int ln16 = lane & 15, quad = lane >> 4;

  f32x4 acc[8][4];
#pragma unroll
  for (int i = 0; i < 8; ++i)
#pragma unroll
    for (int j = 0; j < 4; ++j) acc[i][j] = (f32x4)0.f;

  for (int ks = 0; ks < 32; ++ks) {
    size_t bbase = (size_t)(gb0 * 32 + ks) * 64 + lane;
    f16x8 bh[4], bl[4];
#pragma unroll
    for (int nj = 0; nj < 4; ++nj) {
      bh[nj] = whi[bbase + nj * 2048];
      bl[nj] = wlo[bbase + nj * 2048];
    }
    size_t abase = (size_t)(g0 * 32 + ks) * 64 + lane;
#pragma unroll
    for (int mi = 0; mi < 8; ++mi) {
      f16x8 ah = ahi[abase + mi * 2048];
      f16x8 al = alo[abase + mi * 2048];
#pragma unroll
      for (int nj = 0; nj < 4; ++nj) {
        acc[mi][nj] = __builtin_amdgcn_mfma_f32_16x16x32_f16(ah, bh[nj], acc[mi][nj], 0, 0, 0);
        acc[mi][nj] = __builtin_amdgcn_mfma_f32_16x16x32_f16(al, bh[nj], acc[mi][nj], 0, 0, 0);
        acc[mi][nj] = __builtin_amdgcn_mfma_f32_16x16x32_f16(ah, bl[nj], acc[mi][nj], 0, 0, 0);
      }
    }
  }

  // epilogue: bias + exact GELU + fc2 weight, reduce over hidden
  float s[8][4];
#pragma unroll
  for (int mi = 0; mi < 8; ++mi)
#pragma unroll
    for (int r = 0; r < 4; ++r) s[mi][r] = 0.f;
#pragma unroll
  for (int nj = 0; nj < 4; ++nj) {
    int h = (gb0 + nj) * 16 + ln16;
    float b1 = 0.f, w2 = 0.f;
    if (h < HID_) { b1 = fc1b[h]; w2 = fc2w[h]; }
#pragma unroll
    for (int mi = 0; mi < 8; ++mi)
#pragma unroll
      for (int r = 0; r < 4; ++r) {
        float v = acc[mi][nj][r] * INV_SC2 + b1;
        float gel = 0.5f * v * (1.f + erff(v * 0.70710678118654752440f));
        s[mi][r] = fmaf(gel, w2, s[mi][r]);
      }
  }
#pragma unroll
  for (int mi = 0; mi < 8; ++mi)
#pragma unroll
    for (int r = 0; r < 4; ++r) {
      float v = s[mi][r];
      v += __shfl_xor(v, 1, 64);
      v += __shfl_xor(v, 2, 64);
      v += __shfl_xor(v, 4, 64);
      v += __shfl_xor(v, 8, 64);
      s[mi][r] = v;
    }
  if (ln16 == 0) {
#pragma unroll
    for (int mi = 0; mi < 8; ++mi)
#pragma unroll
      for (int r = 0; r < 4; ++r)
        red[wcol][wrow * 128 + mi * 16 + quad * 4 + r] = s[mi][r];
  }
  __syncthreads();
  partial[(size_t)ht * N_TOK + tb * 256 + tid] = red[0][tid] + red[1][tid];
}

// ---------------- Fallback GEMM (round-2, in-kernel LN+split) -----------------------
__global__ __launch_bounds__(256) void mfma_score_fb(
    const float* __restrict__ emb, const float* __restrict__ attn,
    const float* __restrict__ lnw, const float* __restrict__ lnb,
    const float* __restrict__ mu, const float* __restrict__ rstd,
    const f16x8* __restrict__ whi, const f16x8* __restrict__ wlo,
    const float* __restrict__ fc1b, const float* __restrict__ fc2w,
    float* __restrict__ partial)
{
  __shared__ _Float16 As_hi[MT * LDA];
  __shared__ _Float16 As_lo[MT * LDA];
  __shared__ float red[2][MT];
  int tid = threadIdx.x;
  int lane = tid & 63, w = tid >> 6;
  int m0 = blockIdx.x * MT;
  int ht = blockIdx.y;
  int ln16 = lane & 15, quad = lane >> 4;
  int rowhalf = w & 1, colhalf = w >> 1;
  f32x4 acc[4][4];
#pragma unroll
  for (int i = 0; i < 4; ++i)
#pragma unroll
    for (int j = 0; j < 4; ++j) acc[i][j] = (f32x4)0.f;
  for (int ks = 0; ks < KSTEPS; ++ks) {
    int k0 = ks * 32;
    __syncthreads();
#pragma unroll
    for (int it = 0; it < 4; ++it) {
      int idx = tid + it * 256;
      int row = idx >> 3, c4 = idx & 7;
      int token = m0 + row;
      float4 e = *reinterpret_cast<const float4*>(emb + (size_t)token * D_ + k0 + c4 * 4);
      float av = attn[token], rs = rstd[token];
      float alpha = av * rs;
      float nmr = -mu[token] * rs;
      float4 w4 = *reinterpret_cast<const float4*>(lnw + k0 + c4 * 4);
      float4 b4 = *reinterpret_cast<const float4*>(lnb + k0 + c4 * 4);
      f16x4 hi4, lo4;
      float ys[4] = {fmaf(e.x * alpha, w4.x, fmaf(nmr, w4.x, b4.x)) * SC,
                     fmaf(e.y * alpha, w4.y, fmaf(nmr, w4.y, b4.y)) * SC,
                     fmaf(e.z * alpha, w4.z, fmaf(nmr, w4.z, b4.z)) * SC,
                     fmaf(e.w * alpha, w4.w, fmaf(nmr, w4.w, b4.w)) * SC};
#pragma unroll
      for (int j = 0; j < 4; ++j) {
        _Float16 h = (_Float16)ys[j];
        hi4[j] = h; lo4[j] = (_Float16)(ys[j] - (float)h);
      }
      *reinterpret_cast<f16x4*>(&As_hi[row * LDA + c4 * 4]) = hi4;
      *reinterpret_cast<f16x4*>(&As_lo[row * LDA + c4 * 4]) = lo4;
    }
    __syncthreads();
    f16x8 ah[4], al[4], bh[4], bl[4];
#pragma unroll
    for (int mi = 0; mi < 4; ++mi) {
      int r = rowhalf * 64 + mi * 16 + ln16;
      ah[mi] = *reinterpret_cast<const f16x8*>(&As_hi[r * LDA + quad * 8]);
      al[mi] = *reinterpret_cast<const f16x8*>(&As_lo[r * LDA + quad * 8]);
    }
#pragma unroll
    for (int nj = 0; nj < 4; ++nj) {
      int g = ht * 8 + colhalf * 4 + nj;
      size_t c = ((size_t)(g * 32 + ks) * 4 + quad) * 16 + ln16;
      bh[nj] = whi[c];
      bl[nj] = wlo[c];
    }
#pragma unroll
    for (int mi = 0; mi < 4; ++mi)
#pragma unroll
      for (int nj = 0; nj < 4; ++nj) {
        acc[mi][nj] = __builtin_amdgcn_mfma_f32_16x16x32_f16(ah[mi], bh[nj], acc[mi][nj], 0, 0, 0);
        acc[mi][nj] = __builtin_amdgcn_mfma_f32_16x16x32_f16(al[mi], bh[nj], acc[mi][nj], 0, 0, 0);
        acc[mi][nj] = __builtin_amdgcn_mfma_f32_16x16x32_f16(ah[mi], bl[nj], acc[mi][nj], 0, 0, 0);
      }
  }
  float s[4][4];
#pragma unroll
  for (int mi = 0; mi < 4; ++mi)
#pragma unroll
    for (int r = 0; r < 4; ++r) s[mi][r] = 0.f;
#pragma unroll
  for (int nj = 0; nj < 4; ++nj) {
    int h = ht * HT + colhalf * 64 + nj * 16 + ln16;
    float b1 = 0.f, w2 = 0.f;
    if (h < HID_) { b1 = fc1b[h]; w2 = fc2w[h]; }
#pragma unroll
    for (int mi = 0; mi < 4; ++mi)
#pragma unroll
      for (int r = 0; r < 4; ++r) {
        float v = acc[mi][nj][r] * INV_SC2 + b1;
        float gel = 0.5f * v * (1.f + erff(v * 0.70710678118654752440f));
        s[mi][r] = fmaf(gel, w2, s[mi][r]);
      }
  }
#pragma unroll
  for (int mi = 0; mi < 4; ++mi)
#pragma unroll
    for (int r = 0; r < 4; ++r) {
      float v = s[mi][r];
      v += __shfl_xor(v, 1, 64);
      v += __shfl_xor(v, 2, 64);
      v += __shfl_xor(v, 4, 64);
      v += __shfl_xor(v, 8, 64);
      s[mi][r] = v;
    }
  __syncthreads();
  if (ln16 == 0) {
#pragma unroll
    for (int mi = 0; mi < 4; ++mi)
#pragma unroll
      for (int r = 0; r < 4; ++r)
        red[colhalf][rowhalf * 64 + mi * 16 + quad * 4 + r] = s[mi][r];
  }
  __syncthreads();
  if (tid < MT)
    partial[(size_t)ht * N_TOK + m0 + tid] = red[0][tid] + red[1][tid];
}

// ---------------- Kernel 3: slab-reduce + masked softmax + entropy + K + z ----------
__global__ __launch_bounds__(1024) void softmax_kernel(
    const float* __restrict__ partial, const float* __restrict__ fc2b,
    const float* __restrict__ attn,
    float* __restrict__ out_z, float* __restrict__ rowent, float* __restrict__ rowK)
{
  __shared__ float buf[1024];
  int b = blockIdx.x, tid = threadIdx.x;
  const float* arow = attn + b * T_;
  float sv[4], av[4];
  float f2b = fc2b[0];
#pragma unroll
  for (int q = 0; q < 4; ++q) {
    int t = tid + q * 1024;
    av[q] = arow[t];
    float sc = f2b;
#pragma unroll
    for (int p = 0; p < NHT; ++p) sc += partial[(size_t)p * N_TOK + b * T_ + t];
    sv[q] = (av[q] == 0.f) ? -1e9f : sc;
  }
  float m = fmaxf(fmaxf(sv[0], sv[1]), fmaxf(sv[2], sv[3]));
  buf[tid] = m; __syncthreads();
  for (int s = 512; s > 0; s >>= 1) { if (tid < s) buf[tid] = fmaxf(buf[tid], buf[tid + s]); __syncthreads(); }
  m = buf[0]; __syncthreads();
  float e[4]; float es = 0.f, as = 0.f;
#pragma unroll
  for (int q = 0; q < 4; ++q) { e[q] = expf(sv[q] - m); es += e[q]; as += av[q]; }
  buf[tid] = es; __syncthreads();
  for (int s = 512; s > 0; s >>= 1) { if (tid < s) buf[tid] += buf[tid + s]; __syncthreads(); }
  es = buf[0]; __syncthreads();
  buf[tid] = as; __syncthreads();
  for (int s = 512; s > 0; s >>= 1) { if (tid < s) buf[tid] += buf[tid + s]; __syncthreads(); }
  as = buf[0]; __syncthreads();
  float K = fmaxf(1.f, rintf(RHO_ * as));
  float inv = 1.f / es;
  float ent = 0.f;
#pragma unroll
  for (int q = 0; q < 4; ++q) {
    float p = e[q] * inv;
    out_z[b * T_ + tid + q * 1024] = K * p;
    ent -= p * logf(p + 1e-12f);
  }
  buf[tid] = ent; __syncthreads();
  for (int s = 512; s > 0; s >>= 1) { if (tid < s) buf[tid] += buf[tid + s]; __syncthreads(); }
  if (tid == 0) {
    rowent[b] = buf[0] / logf(fmaxf(as, 1.f));
    rowK[b] = K;
  }
}

// ---------------- Kernel 4: per-row exact top-K mask (stable ties) + scalar out ----
__global__ __launch_bounds__(1024) void topk_kernel(
    const float* __restrict__ zall, float* __restrict__ g,
    const float* __restrict__ rowent, const float* __restrict__ rowK,
    float* __restrict__ out_scalar)
{
  __shared__ float sm[T_];
  __shared__ int s_first, s_last;
  int b = blockIdx.x, tid = threadIdx.x;
  const float* zrow = zall + b * T_;
  for (int t = tid; t < T_; t += 1024) sm[t] = zrow[t];
  __syncthreads();
  for (int k = 2; k <= T_; k <<= 1) {
    for (int j = k >> 1; j > 0; j >>= 1) {
      for (int t = tid; t < T_; t += 1024) {
        int ixj = t ^ j;
        if (ixj > t) {
          float a = sm[t], c = sm[ixj];
          bool desc = ((t & k) == 0);
          if (desc ? (a < c) : (a > c)) { sm[t] = c; sm[ixj] = a; }
        }
      }
      __syncthreads();
    }
  }
  int K = (int)rowK[b];
  float thr = sm[K - 1];
  if (tid == 0) { s_first = T_; s_last = -1; }
  __syncthreads();
  for (int t = tid; t < T_; t += 1024) {
    if (sm[t] == thr) { atomicMin(&s_first, t); atomicMax(&s_last, t); }
  }
  __syncthreads();
  int cgt = s_first;
  int eqTotal = s_last - s_first + 1;
  int need = K - cgt;
  float* grow = g + b * T_;
  bool allEq = (eqTotal == need);
  for (int t = tid; t < T_; t += 1024) {
    float zv = zrow[t];
    if (zv > thr) grow[t] = 1.f;
    else if (zv < thr) grow[t] = 0.f;
    else if (allEq) grow[t] = 1.f;
  }
  __syncthreads();
  if (!allEq && tid == 0) {
    int cnt = 0;
    for (int t = 0; t < T_; ++t) {
      float zv = zrow[t];
      if (zv == thr) { grow[t] = (cnt < need) ? 1.f : 0.f; ++cnt; }
    }
  }
  if (b == 0 && tid == 0) {
    float s = 0.f;
    for (int i = 0; i < B_; ++i) s += rowent[i];
    out_scalar[0] = s * (1.f / B_);
  }
}

extern "C" void kernel_launch(void* const* d_in, const int* in_sizes, int n_in,
                              void* d_out, int out_size, void* d_ws, size_t ws_size,
                              hipStream_t stream)
{
  const float* emb  = (const float*)d_in[0];
  const float* attn = (const float*)d_in[1];
  const float* lnw  = (const float*)d_in[2];
  const float* lnb  = (const float*)d_in[3];
  const float* fc1w = (const float*)d_in[4];
  const float* fc1b = (const float*)d_in[5];
  const float* fc2w = (const float*)d_in[6];
  const float* fc2b = (const float*)d_in[7];

  float* out = (float*)d_out;
  float* g  = out;
  float* z  = out + N_TOK;
  float* ns = out + 2 * N_TOK;

  float* mu      = (float*)d_ws;                    // N_TOK
  float* rstd    = mu + N_TOK;                      // N_TOK
  float* partial = rstd + N_TOK;                    // NHT*N_TOK
  float* rowent  = partial + (size_t)NHT * N_TOK;   // 16
  float* rowK    = rowent + 16;                     // 16
  f16x8* whi     = (f16x8*)(rowK + 16);             // WCHUNKS
  f16x8* wlo     = whi + WCHUNKS;
  f16x8* ahi     = wlo + WCHUNKS;                   // ACHUNKS
  f16x8* alo     = ahi + ACHUNKS;

  size_t needed = (size_t)((char*)(alo + ACHUNKS) - (char*)d_ws);

  ln_stats_kernel<<<N_TOK / 4, 256, 0, stream>>>(emb, attn, mu, rstd);
  wsplit_kernel<<<(WCHUNKS + 255) / 256, 256, 0, stream>>>(fc1w, whi, wlo);
  if (ws_size >= needed) {
    asplit_kernel<<<NG16 * 2, 256, 0, stream>>>(emb, attn, mu, rstd, lnw, lnb, ahi, alo);
    dim3 grid(NHT, N_TOK / 256);
    mfma_score_v3<<<grid, 256, 0, stream>>>(ahi, alo, whi, wlo, fc1b, fc2w, partial);
  } else {
    dim3 grid(N_TOK / MT, NHT);
    mfma_score_fb<<<grid, 256, 0, stream>>>(emb, attn, lnw, lnb, mu, rstd,
                                            whi, wlo, fc1b, fc2w, partial);
  }
  softmax_kernel<<<B_, 1024, 0, stream>>>(partial, fc2b, attn, z, rowent, rowK);
  topk_kernel<<<B_, 1024, 0, stream>>>(z, g, rowent, rowK, ns);
}

// Round 4
// 1174.721 us; speedup vs baseline: 1.8063x; 1.8063x over previous
//
#include <hip/hip_runtime.h>
#include <math.h>

#define B_ 16
#define T_ 4096
#define D_ 1024
#define HID_ 1365
#define NPAD 1408            // 88*16
#define NGRP 88              // NPAD/16
#define N_TOK (B_*T_)
#define RHO_ 0.2f
#define LN_EPS_ 1e-5f
#define SC 1024.0f
#define INV_SC2 (1.0f/(1024.0f*1024.0f))

#define NHT 11               // h-tiles of 128
#define WCHUNKS (NGRP*32*4*16)       // 180224 f16x8 chunks
#define NG16 4096            // 16-token groups
#define ACHUNKS ((size_t)NG16*32*64) // 8388608 f16x8 chunks per buffer

typedef _Float16 f16x8 __attribute__((ext_vector_type(8)));
typedef _Float16 f16x4 __attribute__((ext_vector_type(4)));
typedef float f32x4 __attribute__((ext_vector_type(4)));

// ---------------- Kernel 1: LayerNorm statistics (one wave per token) ----------------
__global__ __launch_bounds__(256) void ln_stats_kernel(
    const float* __restrict__ emb, const float* __restrict__ attn,
    float* __restrict__ mu, float* __restrict__ rstd)
{
  int tid = threadIdx.x;
  int wave = tid >> 6, lane = tid & 63;
  int token = blockIdx.x * 4 + wave;
  const float* p = emb + (size_t)token * D_;
  float a = attn[token];
  float s = 0.f, sq = 0.f;
#pragma unroll
  for (int q = 0; q < 4; ++q) {
    float4 v = *reinterpret_cast<const float4*>(p + lane * 4 + q * 256);
    v.x *= a; v.y *= a; v.z *= a; v.w *= a;
    s  += v.x + v.y + v.z + v.w;
    sq += v.x * v.x + v.y * v.y + v.z * v.z + v.w * v.w;
  }
#pragma unroll
  for (int off = 32; off > 0; off >>= 1) {
    s  += __shfl_down(s, off, 64);
    sq += __shfl_down(sq, off, 64);
  }
  if (lane == 0) {
    float m = s * (1.f / D_);
    float var = sq * (1.f / D_) - m * m;
    if (var < 0.f) var = 0.f;
    mu[token] = m;
    rstd[token] = 1.f / sqrtf(var + LN_EPS_);
  }
}

// ---------------- Kernel 1b: split fc1_w (x1024) into hi/lo f16 in MFMA-frag order ---
__global__ __launch_bounds__(256) void wsplit_kernel(
    const float* __restrict__ fc1w, f16x8* __restrict__ whi, f16x8* __restrict__ wlo)
{
  int c = blockIdx.x * 256 + threadIdx.x;
  if (c >= WCHUNKS) return;
  int ln = c & 15, q = (c >> 4) & 3, ks = (c >> 6) & 31, g = c >> 11;
  int n = g * 16 + ln;
  int k = ks * 32 + q * 8;
  f16x8 hi, lo;
#pragma unroll
  for (int j = 0; j < 8; ++j) {
    float v = (n < HID_) ? fc1w[(size_t)n * D_ + k + j] * SC : 0.f;
    _Float16 h = (_Float16)v;
    hi[j] = h;
    lo[j] = (_Float16)(v - (float)h);
  }
  whi[c] = hi;
  wlo[c] = lo;
}

// ---------------- Kernel 1c: LN-apply + split A into hi/lo f16, MFMA-frag order ------
#define ASTRIDE 516
__global__ __launch_bounds__(256) void asplit_kernel(
    const float* __restrict__ emb, const float* __restrict__ attn,
    const float* __restrict__ mu, const float* __restrict__ rstd,
    const float* __restrict__ lnw, const float* __restrict__ lnb,
    f16x8* __restrict__ ahi, f16x8* __restrict__ alo)
{
  __shared__ float tile[16 * ASTRIDE];
  int tid = threadIdx.x;
  int g = blockIdx.x >> 1, kh = blockIdx.x & 1;
  int kbase = kh * 512;
#pragma unroll
  for (int it = 0; it < 8; ++it) {
    int idx = tid + it * 256;
    int row = idx >> 7, c4 = idx & 127;
    float4 v = *reinterpret_cast<const float4*>(
        emb + (size_t)(g * 16 + row) * D_ + kbase + c4 * 4);
    *reinterpret_cast<float4*>(&tile[row * ASTRIDE + c4 * 4]) = v;
  }
  __syncthreads();
#pragma unroll
  for (int it = 0; it < 4; ++it) {
    int idx = tid + it * 256;
    int ksl = idx >> 6, l = idx & 63;
    int ln = l & 15, q = l >> 4;
    int token = g * 16 + ln;
    float a = attn[token], rs = rstd[token];
    float alpha = a * rs;
    float nmr = -mu[token] * rs;
    int colbase = ksl * 32 + q * 8;
    float4 e0 = *reinterpret_cast<const float4*>(&tile[ln * ASTRIDE + colbase]);
    float4 e1 = *reinterpret_cast<const float4*>(&tile[ln * ASTRIDE + colbase + 4]);
    float ev[8] = {e0.x, e0.y, e0.z, e0.w, e1.x, e1.y, e1.z, e1.w};
    f16x8 hi, lo;
#pragma unroll
    for (int j = 0; j < 8; ++j) {
      int kg = kbase + colbase + j;
      float wv = lnw[kg], bv = lnb[kg];
      float y = fmaf(ev[j] * alpha, wv, fmaf(nmr, wv, bv)) * SC;
      _Float16 h = (_Float16)y;
      hi[j] = h;
      lo[j] = (_Float16)(y - (float)h);
    }
    size_t c = (size_t)(g * 32 + kh * 16 + ksl) * 64 + l;
    ahi[c] = hi;
    alo[c] = lo;
  }
}

// ---------------- Kernel 2 (v4): frag-streaming MFMA GEMM, 64-AGPR wave tile ---------
// flat grid 5632; XCD-swizzled so the 11 ht-blocks of one tb stay on one XCD.
// 256 thr = 4 waves 2x2; wave tile 64 tokens x 64 h (4x4 frags, 3 split products)
__global__ __launch_bounds__(256, 2) void mfma_score_v4(
    const f16x8* __restrict__ ahi, const f16x8* __restrict__ alo,
    const f16x8* __restrict__ whi, const f16x8* __restrict__ wlo,
    const float* __restrict__ fc1b, const float* __restrict__ fc2w,
    float* __restrict__ partial)
{
  __shared__ float red[2][128];
  int tid = threadIdx.x, lane = tid & 63;
  int w = tid >> 6, wrow = w & 1, wcol = w >> 1;
  // XCD-aware swizzle: dispatch maps block i -> XCD i%8 (heuristic, perf-only)
  int flat = blockIdx.x;            // 0..5631 = 8 XCDs * (64 tb * 11 ht)
  int xcd = flat & 7, j = flat >> 3;
  int tb = xcd * 64 + j / NHT;      // 0..511 token-tiles of 128
  int ht = j % NHT;                 // 0..10
  int g0 = tb * 8 + wrow * 4;       // 4 token-groups of 16 per wave
  int gb0 = ht * 8 + wcol * 4;      // 4 h-groups of 16 per wave
  int ln16 = lane & 15, quad = lane >> 4;

  f32x4 acc[4][4];
#pragma unroll
  for (int i = 0; i < 4; ++i)
#pragma unroll
    for (int j2 = 0; j2 < 4; ++j2) acc[i][j2] = (f32x4)0.f;

#pragma unroll 2
  for (int ks = 0; ks < 32; ++ks) {
    size_t bbase = (size_t)(gb0 * 32 + ks) * 64 + lane;
    f16x8 bh[4], bl[4];
#pragma unroll
    for (int nj = 0; nj < 4; ++nj) {
      bh[nj] = whi[bbase + nj * 2048];
      bl[nj] = wlo[bbase + nj * 2048];
    }
    size_t abase = (size_t)(g0 * 32 + ks) * 64 + lane;
    f16x8 ah[4], al[4];
#pragma unroll
    for (int mi = 0; mi < 4; ++mi) {
      ah[mi] = ahi[abase + mi * 2048];
      al[mi] = alo[abase + mi * 2048];
    }
#pragma unroll
    for (int mi = 0; mi < 4; ++mi)
#pragma unroll
      for (int nj = 0; nj < 4; ++nj) {
        acc[mi][nj] = __builtin_amdgcn_mfma_f32_16x16x32_f16(ah[mi], bh[nj], acc[mi][nj], 0, 0, 0);
        acc[mi][nj] = __builtin_amdgcn_mfma_f32_16x16x32_f16(al[mi], bh[nj], acc[mi][nj], 0, 0, 0);
        acc[mi][nj] = __builtin_amdgcn_mfma_f32_16x16x32_f16(ah[mi], bl[nj], acc[mi][nj], 0, 0, 0);
      }
  }

  // ---- epilogue: bias + exact GELU + fc2 weight, reduce over hidden ----
  float s[4][4];
#pragma unroll
  for (int mi = 0; mi < 4; ++mi)
#pragma unroll
    for (int r = 0; r < 4; ++r) s[mi][r] = 0.f;
#pragma unroll
  for (int nj = 0; nj < 4; ++nj) {
    int h = (gb0 + nj) * 16 + ln16;
    float b1 = 0.f, w2 = 0.f;
    if (h < HID_) { b1 = fc1b[h]; w2 = fc2w[h]; }
#pragma unroll
    for (int mi = 0; mi < 4; ++mi)
#pragma unroll
      for (int r = 0; r < 4; ++r) {
        float v = acc[mi][nj][r] * INV_SC2 + b1;
        float gel = 0.5f * v * (1.f + erff(v * 0.70710678118654752440f));
        s[mi][r] = fmaf(gel, w2, s[mi][r]);
      }
  }
#pragma unroll
  for (int mi = 0; mi < 4; ++mi)
#pragma unroll
    for (int r = 0; r < 4; ++r) {
      float v = s[mi][r];
      v += __shfl_xor(v, 1, 64);
      v += __shfl_xor(v, 2, 64);
      v += __shfl_xor(v, 4, 64);
      v += __shfl_xor(v, 8, 64);
      s[mi][r] = v;
    }
  if (ln16 == 0) {
#pragma unroll
    for (int mi = 0; mi < 4; ++mi)
#pragma unroll
      for (int r = 0; r < 4; ++r)
        red[wcol][wrow * 64 + mi * 16 + quad * 4 + r] = s[mi][r];
  }
  __syncthreads();
  if (tid < 128)
    partial[(size_t)ht * N_TOK + tb * 128 + tid] = red[0][tid] + red[1][tid];
}

// ---------------- Kernel 3: slab-reduce + masked softmax + entropy + K + z ----------
__global__ __launch_bounds__(1024) void softmax_kernel(
    const float* __restrict__ partial, const float* __restrict__ fc2b,
    const float* __restrict__ attn,
    float* __restrict__ out_z, float* __restrict__ rowent, float* __restrict__ rowK)
{
  __shared__ float buf[1024];
  int b = blockIdx.x, tid = threadIdx.x;
  const float* arow = attn + b * T_;
  float sv[4], av[4];
  float f2b = fc2b[0];
#pragma unroll
  for (int q = 0; q < 4; ++q) {
    int t = tid + q * 1024;
    av[q] = arow[t];
    float sc = f2b;
#pragma unroll
    for (int p = 0; p < NHT; ++p) sc += partial[(size_t)p * N_TOK + b * T_ + t];
    sv[q] = (av[q] == 0.f) ? -1e9f : sc;
  }
  float m = fmaxf(fmaxf(sv[0], sv[1]), fmaxf(sv[2], sv[3]));
  buf[tid] = m; __syncthreads();
  for (int s = 512; s > 0; s >>= 1) { if (tid < s) buf[tid] = fmaxf(buf[tid], buf[tid + s]); __syncthreads(); }
  m = buf[0]; __syncthreads();
  float e[4]; float es = 0.f, as = 0.f;
#pragma unroll
  for (int q = 0; q < 4; ++q) { e[q] = expf(sv[q] - m); es += e[q]; as += av[q]; }
  buf[tid] = es; __syncthreads();
  for (int s = 512; s > 0; s >>= 1) { if (tid < s) buf[tid] += buf[tid + s]; __syncthreads(); }
  es = buf[0]; __syncthreads();
  buf[tid] = as; __syncthreads();
  for (int s = 512; s > 0; s >>= 1) { if (tid < s) buf[tid] += buf[tid + s]; __syncthreads(); }
  as = buf[0]; __syncthreads();
  float K = fmaxf(1.f, rintf(RHO_ * as));
  float inv = 1.f / es;
  float ent = 0.f;
#pragma unroll
  for (int q = 0; q < 4; ++q) {
    float p = e[q] * inv;
    out_z[b * T_ + tid + q * 1024] = K * p;
    ent -= p * logf(p + 1e-12f);
  }
  buf[tid] = ent; __syncthreads();
  for (int s = 512; s > 0; s >>= 1) { if (tid < s) buf[tid] += buf[tid + s]; __syncthreads(); }
  if (tid == 0) {
    rowent[b] = buf[0] / logf(fmaxf(as, 1.f));
    rowK[b] = K;
  }
}

// ---------------- Kernel 4: per-row exact top-K mask (stable ties) + scalar out ----
__global__ __launch_bounds__(1024) void topk_kernel(
    const float* __restrict__ zall, float* __restrict__ g,
    const float* __restrict__ rowent, const float* __restrict__ rowK,
    float* __restrict__ out_scalar)
{
  __shared__ float sm[T_];
  __shared__ int s_first, s_last;
  int b = blockIdx.x, tid = threadIdx.x;
  const float* zrow = zall + b * T_;
  for (int t = tid; t < T_; t += 1024) sm[t] = zrow[t];
  __syncthreads();
  for (int k = 2; k <= T_; k <<= 1) {
    for (int j = k >> 1; j > 0; j >>= 1) {
      for (int t = tid; t < T_; t += 1024) {
        int ixj = t ^ j;
        if (ixj > t) {
          float a = sm[t], c = sm[ixj];
          bool desc = ((t & k) == 0);
          if (desc ? (a < c) : (a > c)) { sm[t] = c; sm[ixj] = a; }
        }
      }
      __syncthreads();
    }
  }
  int K = (int)rowK[b];
  float thr = sm[K - 1];
  if (tid == 0) { s_first = T_; s_last = -1; }
  __syncthreads();
  for (int t = tid; t < T_; t += 1024) {
    if (sm[t] == thr) { atomicMin(&s_first, t); atomicMax(&s_last, t); }
  }
  __syncthreads();
  int cgt = s_first;
  int eqTotal = s_last - s_first + 1;
  int need = K - cgt;
  float* grow = g + b * T_;
  bool allEq = (eqTotal == need);
  for (int t = tid; t < T_; t += 1024) {
    float zv = zrow[t];
    if (zv > thr) grow[t] = 1.f;
    else if (zv < thr) grow[t] = 0.f;
    else if (allEq) grow[t] = 1.f;
  }
  __syncthreads();
  if (!allEq && tid == 0) {
    int cnt = 0;
    for (int t = 0; t < T_; ++t) {
      float zv = zrow[t];
      if (zv == thr) { grow[t] = (cnt < need) ? 1.f : 0.f; ++cnt; }
    }
  }
  if (b == 0 && tid == 0) {
    float s = 0.f;
    for (int i = 0; i < B_; ++i) s += rowent[i];
    out_scalar[0] = s * (1.f / B_);
  }
}

extern "C" void kernel_launch(void* const* d_in, const int* in_sizes, int n_in,
                              void* d_out, int out_size, void* d_ws, size_t ws_size,
                              hipStream_t stream)
{
  const float* emb  = (const float*)d_in[0];
  const float* attn = (const float*)d_in[1];
  const float* lnw  = (const float*)d_in[2];
  const float* lnb  = (const float*)d_in[3];
  const float* fc1w = (const float*)d_in[4];
  const float* fc1b = (const float*)d_in[5];
  const float* fc2w = (const float*)d_in[6];
  const float* fc2b = (const float*)d_in[7];

  float* out = (float*)d_out;
  float* g  = out;
  float* z  = out + N_TOK;
  float* ns = out + 2 * N_TOK;

  float* mu      = (float*)d_ws;                    // N_TOK
  float* rstd    = mu + N_TOK;                      // N_TOK
  float* partial = rstd + N_TOK;                    // NHT*N_TOK
  float* rowent  = partial + (size_t)NHT * N_TOK;   // 16
  float* rowK    = rowent + 16;                     // 16
  f16x8* whi     = (f16x8*)(rowK + 16);             // WCHUNKS
  f16x8* wlo     = whi + WCHUNKS;
  f16x8* ahi     = wlo + WCHUNKS;                   // ACHUNKS
  f16x8* alo     = ahi + ACHUNKS;

  ln_stats_kernel<<<N_TOK / 4, 256, 0, stream>>>(emb, attn, mu, rstd);
  wsplit_kernel<<<(WCHUNKS + 255) / 256, 256, 0, stream>>>(fc1w, whi, wlo);
  asplit_kernel<<<NG16 * 2, 256, 0, stream>>>(emb, attn, mu, rstd, lnw, lnb, ahi, alo);
  mfma_score_v4<<<8 * 64 * NHT, 256, 0, stream>>>(ahi, alo, whi, wlo, fc1b, fc2w, partial);
  softmax_kernel<<<B_, 1024, 0, stream>>>(partial, fc2b, attn, z, rowent, rowK);
  topk_kernel<<<B_, 1024, 0, stream>>>(z, g, rowent, rowK, ns);
}